// Round 9
// baseline (3836.947 us; speedup 1.0000x reference)
//
#include <hip/hip_runtime.h>
#include <hip/hip_bf16.h>

// Problem constants
#define BSN   2500   // nodes
#define TT    400    // time steps
#define DIN   16     // input dim
#define HS    32     // hidden dim
#define G4    128    // 4*HS
#define NBLK  157    // blocks (16 rows each)
#define NTHR  512    // 8 waves: 2 waves/SIMD for latency overlap
#define ROWS  16     // nodes per block (MFMA M-tile)
#define MPAD  (NBLK * ROWS)   // 2512 padded rows
#define KPAD  2528            // 79*32 (R3/R7-proven layout)
#define NCHUNK 79
#define ADJW  2536            // adj LDS row stride (ushorts)
#define HPAD  36              // fp32 LDS row pad

// Flags are PACKED (4-B stride): 157 flags span 10 cache lines, so one
// polling wave reads 4 contiguous lines (coalesced) instead of 64 distinct
// lines. R8 post-mortem: 64-B-strided flags made the spin loop saturate the
// LLC request rate (~25K line-requests per poll period grid-wide).

// workspace layout (bytes) — flags block shrunk, adj offset unchanged
#define WS_FLAGS_OFF  0
#define WS_ADJ_OFF    16384
#define WS_ADJ_BYTES  ((size_t)MPAD * KPAD * 2)
#define WS_QT_OFF     (WS_ADJ_OFF + WS_ADJ_BYTES)
#define QT_SLICE      ((size_t)HS * KPAD)
#define WS_NEED_RING  (WS_QT_OFF + (size_t)TT * QT_SLICE * 2)   // ~77.4 MB

typedef __attribute__((ext_vector_type(8))) __bf16 bf16x8;
typedef __attribute__((ext_vector_type(4))) float floatx4;
typedef unsigned short ushort_t;
typedef unsigned long long u64_t;

__device__ __forceinline__ float sigmoid_fast(float v) {
    return 1.0f / (1.0f + __expf(-v));
}
__device__ __forceinline__ float tanh_fast(float v) {
    float e = __expf(2.0f * v);
    return 1.0f - 2.0f / (e + 1.0f);
}
__device__ __forceinline__ ushort_t f2bf(float f) {
    union { float f; unsigned u; } x; x.f = f;
    unsigned r = x.u + 0x7fffu + ((x.u >> 16) & 1u);  // RNE
    return (ushort_t)(r >> 16);
}

// Sentinel: if the cooperative launch is rejected at submit time, out keeps
// 12345.0 -> absmax ~1.23e4 (vs 1.0156 "untouched", 3.9e-3 "correct").
__global__ void sentinel(float* __restrict__ out, int n) {
    int i = blockIdx.x * blockDim.x + threadIdx.x;
    if (i < n) out[i] = 12345.0f;
}

// Per-launch prep (d_ws re-poisoned 0xAA before every timed launch).
__global__ void prep(const float* __restrict__ adj, ushort_t* __restrict__ adj_bf,
                     ushort_t* __restrict__ qT, unsigned* __restrict__ flags) {
    const size_t idx0 = (size_t)blockIdx.x * blockDim.x + threadIdx.x;
    const size_t stride = (size_t)gridDim.x * blockDim.x;
    const size_t total = (size_t)MPAD * KPAD;
    for (size_t idx = idx0; idx < total; idx += stride) {
        int r = (int)(idx / KPAD);
        int k = (int)(idx - (size_t)r * KPAD);
        float v = (r < BSN && k < BSN) ? adj[(size_t)r * BSN + k] : 0.0f;
        adj_bf[idx] = f2bf(v);
    }
    for (size_t idx = idx0; idx < 2 * QT_SLICE; idx += stride) qT[idx] = 0;
    if (idx0 < 256) flags[idx0] = 0;
}

#define QLOAD(p) __hip_atomic_load((p), __ATOMIC_RELAXED, __HIP_MEMORY_SCOPE_AGENT)

// Ring-mode P2: full prefetch — all NC chunks' q loads issued before any MFMA.
template<int NC>
__device__ __forceinline__ void p2_full(const ushort_t* __restrict__ arow,
                                        const ushort_t* __restrict__ q0r,
                                        const ushort_t* __restrict__ q1r,
                                        const int cbeg,
                                        floatx4& acc0, floatx4& acc1) {
    bf16x8 b0[NC], b1[NC];
#pragma unroll
    for (int i = 0; i < NC; i++) {
        b0[i] = *(const bf16x8*)(q0r + (cbeg + i) * 32);
        b1[i] = *(const bf16x8*)(q1r + (cbeg + i) * 32);
    }
#pragma unroll
    for (int i = 0; i < NC; i++) {
        bf16x8 av = *(const bf16x8*)(arow + (cbeg + i) * 32);
        acc0 = __builtin_amdgcn_mfma_f32_16x16x32_bf16(av, b0[i], acc0, 0, 0, 0);
        acc1 = __builtin_amdgcn_mfma_f32_16x16x32_bf16(av, b1[i], acc1, 0, 0, 0);
    }
}

// Persistent cooperative kernel, 512 threads (8 waves), block b owns nodes
// [16b,16b+16). RING=true: per-step qT ring, plain prefetched loads.
// RING=false: 2-slot parity buffer + atomic loads (fallback).
template<bool RING>
__global__ void __launch_bounds__(NTHR, 2) rgcn_main(
    const float* __restrict__ x,      // [BSN][TT][DIN]
    const float* __restrict__ W_ih,   // [DIN][G4]
    const float* __restrict__ W_hh,   // [HS][G4]
    const float* __restrict__ bias,   // [G4]
    const float* __restrict__ W_q,    // [HS][HS]
    const float* __restrict__ b_q,    // [HS]
    const float* __restrict__ W_d,    // [HS]
    const float* __restrict__ b_d,    // [1]
    const ushort_t* __restrict__ adj_bf, // [MPAD][KPAD] bf16
    ushort_t* __restrict__ qT,        // ring: [TT][HS][KPAD]; parity: [2][HS][KPAD]
    unsigned* __restrict__ flags,     // [NBLK] PACKED generation flags (4-B stride)
    float* __restrict__ out)          // [BSN][TT]
{
    const int tid  = threadIdx.x;
    const int blk  = blockIdx.x;
    const int base = blk * ROWS;
    const int wv   = tid >> 6;        // wave 0..7
    const int lane = tid & 63;

    __shared__ __align__(16) ushort_t adj_lds[ROWS * ADJW];   // ~81 KB, staged once
    __shared__ __align__(16) float x_lds[ROWS][DIN];
    __shared__ __align__(16) float h_lds[ROWS][HPAD];
    __shared__ __align__(16) float c_lds[ROWS][HPAD];
    __shared__ __align__(16) float q_lds[ROWS][HPAD];
    __shared__ float gates_lds[ROWS][G4];
    __shared__ float part[8][2][16][16];      // [wave][ntile][row][col], 16 KB

    // ---- per-thread weights ----
    const int u2 = tid & 63;
    float wih0[DIN], wih1[DIN], whh0[HS], whh1[HS];
#pragma unroll
    for (int k = 0; k < DIN; k++) { wih0[k] = W_ih[k*G4 + u2]; wih1[k] = W_ih[k*G4 + u2 + 64]; }
#pragma unroll
    for (int k = 0; k < HS; k++)  { whh0[k] = W_hh[k*G4 + u2]; whh1[k] = W_hh[k*G4 + u2 + 64]; }
    const float bu0 = bias[u2], bu1 = bias[u2 + 64];

    // P1b/P3 mapping: thread = (node nq = tid>>5 in 0..15, hidden hq = tid&31) — wave-local
    const int hq = tid & 31;
    const int nq = tid >> 5;
    float wq[HS];
#pragma unroll
    for (int k = 0; k < HS; k++) wq[k] = W_q[k*HS + hq];
    const float bqv = b_q[hq];
    const float wdv = W_d[hq];
    const float bdv = b_d[0];

    // ---- stage adj rows to LDS once ----
    {
        const int n16_per_row = KPAD / 8;           // 316 uint4 per row
        for (int i = tid; i < ROWS * n16_per_row; i += NTHR) {
            int r = i / n16_per_row, o = i - r * n16_per_row;
            ((uint4*)(adj_lds + r * ADJW))[o] =
                ((const uint4*)(adj_bf + (size_t)(base + r) * KPAD))[o];
        }
    }
    for (int i = tid; i < ROWS * HPAD; i += NTHR) {
        (&h_lds[0][0])[i] = 0.0f;
        (&c_lds[0][0])[i] = 0.0f;
    }
    __syncthreads();

    for (int t = 0; t < TT; t++) {
        const unsigned phase = (unsigned)(t + 1);
        ushort_t* qbuf = qT + (size_t)(RING ? t : (t & 1)) * QT_SLICE;

        // ---- P1b: q = tanh(h @ W_q + b_q); one q value per thread ----
        {
            float a = bqv;
#pragma unroll
            for (int k4 = 0; k4 < HS/4; k4++) {
                float4 hv = *(const float4*)&h_lds[nq][k4*4];
                a = fmaf(hv.x, wq[k4*4+0], a);
                a = fmaf(hv.y, wq[k4*4+1], a);
                a = fmaf(hv.z, wq[k4*4+2], a);
                a = fmaf(hv.w, wq[k4*4+3], a);
            }
            q_lds[nq][hq] = tanh_fast(a);
        }
        __syncthreads();

        // ---- publish q: packed uint, agent-scope relaxed (write-through to LLC) ----
        if (tid < 256) {
            const int h0 = tid >> 3;       // 0..31
            const int pr = tid & 7;        // node pair
            unsigned val = (unsigned)f2bf(q_lds[2*pr][h0])
                         | ((unsigned)f2bf(q_lds[2*pr + 1][h0]) << 16);
            unsigned* p = (unsigned*)(qbuf + (size_t)h0 * KPAD + base) + pr;
            __hip_atomic_store(p, val, __ATOMIC_RELAXED, __HIP_MEMORY_SCOPE_AGENT);
        }

        // ==== drain shadow: local work overlaps the store->LLC round trip ====
        if (lane < 32) {
            const int node = 2*wv + (lane >> 4), k = lane & 15;
            const int gn = base + node;
            x_lds[node][k] = (gn < BSN) ? x[(size_t)gn * (TT*DIN) + (size_t)t*DIN + k] : 0.0f;
        }
#pragma unroll
        for (int j = 0; j < 2; j++) {
            const int nn = 2*wv + j;
            float a0 = bu0, a1 = bu1;
#pragma unroll
            for (int k4 = 0; k4 < DIN/4; k4++) {
                float4 xv = *(const float4*)&x_lds[nn][k4*4];
                a0 = fmaf(xv.x, wih0[k4*4+0], a0); a1 = fmaf(xv.x, wih1[k4*4+0], a1);
                a0 = fmaf(xv.y, wih0[k4*4+1], a0); a1 = fmaf(xv.y, wih1[k4*4+1], a1);
                a0 = fmaf(xv.z, wih0[k4*4+2], a0); a1 = fmaf(xv.z, wih1[k4*4+2], a1);
                a0 = fmaf(xv.w, wih0[k4*4+3], a0); a1 = fmaf(xv.w, wih1[k4*4+3], a1);
            }
#pragma unroll
            for (int k4 = 0; k4 < HS/4; k4++) {
                float4 hv = *(const float4*)&h_lds[nn][k4*4];
                a0 = fmaf(hv.x, whh0[k4*4+0], a0); a1 = fmaf(hv.x, whh1[k4*4+0], a1);
                a0 = fmaf(hv.y, whh0[k4*4+1], a0); a1 = fmaf(hv.y, whh1[k4*4+1], a1);
                a0 = fmaf(hv.z, whh0[k4*4+2], a0); a1 = fmaf(hv.z, whh1[k4*4+2], a1);
                a0 = fmaf(hv.w, whh0[k4*4+3], a0); a1 = fmaf(hv.w, whh1[k4*4+3], a1);
            }
            gates_lds[nn][u2]      = sigmoid_fast(a0);
            gates_lds[nn][u2 + 64] = (u2 < HS) ? tanh_fast(a1) : sigmoid_fast(a1);
        }

        // ---- drain q stores, then arrive (one 4-B store, packed array) ----
        asm volatile("s_waitcnt vmcnt(0)" ::: "memory");
        __syncthreads();
        if (tid == 0) {
            __hip_atomic_store(flags + blk, phase,
                               __ATOMIC_RELAXED, __HIP_MEMORY_SCOPE_AGENT);
        }

        // ---- wait: thread i polls flags[i] — PACKED, so each wave's 64 loads
        //      are 4 coalesced lines; s_sleep backoff keeps LLC pressure low ----
        if (tid < NBLK) {
            const unsigned* f = flags + tid;
            while (__hip_atomic_load(f, __ATOMIC_RELAXED, __HIP_MEMORY_SCOPE_AGENT) < phase)
                __builtin_amdgcn_s_sleep(1);
        }
        __syncthreads();

        // ---- P2: agg = adj(LDS) @ q(LLC); wave w: contiguous chunks [10w, 10w+10) ----
        {
            floatx4 acc0 = {0.f,0.f,0.f,0.f}, acc1 = {0.f,0.f,0.f,0.f};
            const int mcol = lane & 15;
            const int kb   = lane >> 4;
            const ushort_t* arow = adj_lds + mcol * ADJW + kb*8;   // LDS

            if constexpr (RING) {
                const ushort_t* q0r = qbuf + (size_t)mcol        * KPAD + kb*8;
                const ushort_t* q1r = qbuf + (size_t)(mcol + 16) * KPAD + kb*8;
                if (wv < 7) p2_full<10>(arow, q0r, q1r, wv * 10, acc0, acc1);
                else        p2_full<9>(arow, q0r, q1r, 70,       acc0, acc1);
            } else {
                const u64_t* q0 = (const u64_t*)(qbuf + (size_t)mcol        * KPAD) + kb*2;
                const u64_t* q1 = (const u64_t*)(qbuf + (size_t)(mcol + 16) * KPAD) + kb*2;
                const int cbeg = wv * 10;
                const int cend = (cbeg + 10 < NCHUNK) ? cbeg + 10 : NCHUNK;
                for (int c = cbeg; c < cend; c++) {
                    bf16x8 av = *(const bf16x8*)(arow + c*32);
                    union { u64_t u[2]; bf16x8 v; } b0, b1;
                    b0.u[0] = QLOAD(q0 + c*8);
                    b0.u[1] = QLOAD(q0 + c*8 + 1);
                    b1.u[0] = QLOAD(q1 + c*8);
                    b1.u[1] = QLOAD(q1 + c*8 + 1);
                    acc0 = __builtin_amdgcn_mfma_f32_16x16x32_bf16(av, b0.v, acc0, 0, 0, 0);
                    acc1 = __builtin_amdgcn_mfma_f32_16x16x32_bf16(av, b1.v, acc1, 0, 0, 0);
                }
            }

            // D layout: col=lane&15, row=(lane>>4)*4+reg
#pragma unroll
            for (int r = 0; r < 4; r++) {
                part[wv][0][kb*4 + r][mcol] = acc0[r];
                part[wv][1][kb*4 + r][mcol] = acc1[r];
            }
        }
        __syncthreads();

        // ---- P3: cell/hidden update + fused output head ----
        {
            const int ntile = hq >> 4, col = hq & 15;
            float agg = 0.0f;
#pragma unroll
            for (int w = 0; w < 8; w++) agg += part[w][ntile][nq][col];
            float iv = gates_lds[nq][hq];
            float fv = gates_lds[nq][HS + hq];
            float gv = gates_lds[nq][2*HS + hq];
            float ov = gates_lds[nq][3*HS + hq];
            float cv = fv * (c_lds[nq][hq] + agg) + iv * gv;
            float hv = ov * tanh_fast(cv);
            c_lds[nq][hq] = cv;
            h_lds[nq][hq] = hv;
            float p = hv * wdv;
            p += __shfl_xor(p, 16);
            p += __shfl_xor(p, 8);
            p += __shfl_xor(p, 4);
            p += __shfl_xor(p, 2);
            p += __shfl_xor(p, 1);
            if (hq == 0) {
                int gn = base + nq;
                if (gn < BSN) out[(size_t)gn * TT + t] = p + bdv;
            }
        }
        __syncthreads();
    }
}

extern "C" void kernel_launch(void* const* d_in, const int* in_sizes, int n_in,
                              void* d_out, int out_size, void* d_ws, size_t ws_size,
                              hipStream_t stream) {
    const float* x    = (const float*)d_in[0];
    const float* adj  = (const float*)d_in[1];
    const float* W_ih = (const float*)d_in[2];
    const float* W_hh = (const float*)d_in[3];
    const float* bias = (const float*)d_in[4];
    const float* W_q  = (const float*)d_in[5];
    const float* b_q  = (const float*)d_in[6];
    const float* W_d  = (const float*)d_in[7];
    const float* b_d  = (const float*)d_in[8];
    float* out = (float*)d_out;

    unsigned* flags = (unsigned*)((char*)d_ws + WS_FLAGS_OFF);
    ushort_t* adj_bf = (ushort_t*)((char*)d_ws + WS_ADJ_OFF);
    ushort_t* qT = (ushort_t*)((char*)d_ws + WS_QT_OFF);

    const bool ring = (ws_size >= WS_NEED_RING);   // constant across calls -> graph-safe

    // sentinel first: if the cooperative launch below is rejected, out keeps 12345.0
    hipLaunchKernelGGL(sentinel, dim3((out_size + 255) / 256), dim3(256), 0, stream,
                       out, out_size);
    hipLaunchKernelGGL(prep, dim3(2048), dim3(256), 0, stream, adj, adj_bf, qT, flags);

    const ushort_t* adj_bf_c = adj_bf;
    void* args[] = {
        (void*)&x, (void*)&W_ih, (void*)&W_hh, (void*)&bias, (void*)&W_q,
        (void*)&b_q, (void*)&W_d, (void*)&b_d, (void*)&adj_bf_c, (void*)&qT,
        (void*)&flags, (void*)&out
    };
    if (ring) {
        hipLaunchCooperativeKernel((void*)&rgcn_main<true>, dim3(NBLK), dim3(NTHR),
                                   args, 0, stream);
    } else {
        hipLaunchCooperativeKernel((void*)&rgcn_main<false>, dim3(NBLK), dim3(NTHR),
                                   args, 0, stream);
    }
}

// Round 10
// 3111.341 us; speedup vs baseline: 1.2332x; 1.2332x over previous
//
#include <hip/hip_runtime.h>
#include <hip/hip_bf16.h>

// Problem constants
#define BSN   2500   // nodes
#define TT    400    // time steps
#define DIN   16     // input dim
#define HS    32     // hidden dim
#define G4    128    // 4*HS
#define NBLK  157    // blocks (16 rows each)
#define NTHR  512    // 8 waves: 2 waves/SIMD
#define ROWS  16     // nodes per block (MFMA M-tile)
#define MPAD  (NBLK * ROWS)   // 2512 padded rows
#define KPAD  2528            // 79*32 (proven layout)
#define NCHUNK 79
#define ADJW  2536            // adj LDS row stride (ushorts)
#define HPAD  36              // fp32 LDS row pad
#define FLAGSTRIDE 16         // uints between flags (64 B) — R8-proven: one LLC line
                              // per flag avoids the R9 packed-line hotspot

// workspace layout (bytes)
#define WS_FLAGS_OFF  0
#define WS_ADJ_OFF    16384
#define WS_ADJ_BYTES  ((size_t)MPAD * KPAD * 2)
#define WS_QT_OFF     (WS_ADJ_OFF + WS_ADJ_BYTES)
#define QT_SLICE      ((size_t)HS * KPAD)
#define WS_NEED_RING  (WS_QT_OFF + (size_t)TT * QT_SLICE * 2)   // ~77.4 MB

typedef __attribute__((ext_vector_type(8))) __bf16 bf16x8;
typedef __attribute__((ext_vector_type(4))) float floatx4;
typedef unsigned short ushort_t;
typedef unsigned long long u64_t;

__device__ __forceinline__ float sigmoid_fast(float v) {
    return 1.0f / (1.0f + __expf(-v));
}
__device__ __forceinline__ float tanh_fast(float v) {
    float e = __expf(2.0f * v);
    return 1.0f - 2.0f / (e + 1.0f);
}
__device__ __forceinline__ ushort_t f2bf(float f) {
    union { float f; unsigned u; } x; x.f = f;
    unsigned r = x.u + 0x7fffu + ((x.u >> 16) & 1u);  // RNE
    return (ushort_t)(r >> 16);
}

// Sentinel: if the cooperative launch is rejected at submit time, out keeps
// 12345.0 -> absmax ~1.23e4 (vs 1.0156 "untouched", 3.9e-3 "correct").
__global__ void sentinel(float* __restrict__ out, int n) {
    int i = blockIdx.x * blockDim.x + threadIdx.x;
    if (i < n) out[i] = 12345.0f;
}

// Per-launch prep (d_ws re-poisoned 0xAA before every timed launch).
__global__ void prep(const float* __restrict__ adj, ushort_t* __restrict__ adj_bf,
                     ushort_t* __restrict__ qT, unsigned* __restrict__ flags) {
    const size_t idx0 = (size_t)blockIdx.x * blockDim.x + threadIdx.x;
    const size_t stride = (size_t)gridDim.x * blockDim.x;
    const size_t total = (size_t)MPAD * KPAD;
    for (size_t idx = idx0; idx < total; idx += stride) {
        int r = (int)(idx / KPAD);
        int k = (int)(idx - (size_t)r * KPAD);
        float v = (r < BSN && k < BSN) ? adj[(size_t)r * BSN + k] : 0.0f;
        adj_bf[idx] = f2bf(v);
    }
    for (size_t idx = idx0; idx < 2 * QT_SLICE; idx += stride) qT[idx] = 0;
    if (idx0 < NBLK * FLAGSTRIDE) flags[idx0] = 0;
}

#define QLOAD(p) __hip_atomic_load((p), __ATOMIC_RELAXED, __HIP_MEMORY_SCOPE_AGENT)

// Ring-mode P2: full prefetch — all NC chunks' q loads issued before any MFMA.
template<int NC>
__device__ __forceinline__ void p2_full(const ushort_t* __restrict__ arow,
                                        const ushort_t* __restrict__ q0r,
                                        const ushort_t* __restrict__ q1r,
                                        const int cbeg,
                                        floatx4& acc0, floatx4& acc1) {
    bf16x8 b0[NC], b1[NC];
#pragma unroll
    for (int i = 0; i < NC; i++) {
        b0[i] = *(const bf16x8*)(q0r + (cbeg + i) * 32);
        b1[i] = *(const bf16x8*)(q1r + (cbeg + i) * 32);
    }
#pragma unroll
    for (int i = 0; i < NC; i++) {
        bf16x8 av = *(const bf16x8*)(arow + (cbeg + i) * 32);
        acc0 = __builtin_amdgcn_mfma_f32_16x16x32_bf16(av, b0[i], acc0, 0, 0, 0);
        acc1 = __builtin_amdgcn_mfma_f32_16x16x32_bf16(av, b1[i], acc1, 0, 0, 0);
    }
}

// Persistent cooperative kernel, 512 threads (8 waves), block b owns nodes
// [16b,16b+16). R10 delta vs R8: ALL per-step weight reads come from LDS
// (float4-packed, staged once) — R8's VGPR=104 proved the compiler re-loaded
// ~256 KB/block/step of weights through L1/L2 every step.
template<bool RING>
__global__ void __launch_bounds__(NTHR, 2) rgcn_main(
    const float* __restrict__ x,      // [BSN][TT][DIN]
    const float* __restrict__ W_ih,   // [DIN][G4]
    const float* __restrict__ W_hh,   // [HS][G4]
    const float* __restrict__ bias,   // [G4]
    const float* __restrict__ W_q,    // [HS][HS]
    const float* __restrict__ b_q,    // [HS]
    const float* __restrict__ W_d,    // [HS]
    const float* __restrict__ b_d,    // [1]
    const ushort_t* __restrict__ adj_bf, // [MPAD][KPAD] bf16
    ushort_t* __restrict__ qT,        // ring: [TT][HS][KPAD]; parity: [2][HS][KPAD]
    unsigned* __restrict__ flags,     // [NBLK] generation flags, FLAGSTRIDE apart
    float* __restrict__ out)          // [BSN][TT]
{
    const int tid  = threadIdx.x;
    const int blk  = blockIdx.x;
    const int base = blk * ROWS;
    const int wv   = tid >> 6;        // wave 0..7
    const int lane = tid & 63;

    __shared__ __align__(16) ushort_t adj_lds[ROWS * ADJW];   // ~81 KB, staged once
    __shared__ __align__(16) float x_lds[ROWS][DIN];
    __shared__ __align__(16) float h_lds[ROWS][HPAD];
    __shared__ __align__(16) float c_lds[ROWS][HPAD];
    __shared__ __align__(16) float q_lds[ROWS][HPAD];
    __shared__ float gates_lds[ROWS][G4];
    __shared__ float part[8][2][16][16];      // [wave][ntile][row][col], 16 KB
    // weights, float4-packed along K (staged once; conflict-free lane pattern)
    __shared__ __align__(16) float4 wih4[DIN/4][G4];   // 8 KB
    __shared__ __align__(16) float4 whh4[HS/4][G4];    // 16 KB
    __shared__ __align__(16) float4 wq4[HS/4][HS];     // 4 KB

    const int u2 = tid & 63;
    const float bu0 = bias[u2], bu1 = bias[u2 + 64];

    // P1b/P3 mapping: thread = (node nq = tid>>5 in 0..15, hidden hq = tid&31)
    const int hq = tid & 31;
    const int nq = tid >> 5;
    const float bqv = b_q[hq];
    const float wdv = W_d[hq];
    const float bdv = b_d[0];

    // ---- stage weights to LDS once ----
    for (int i = tid; i < (DIN/4) * G4; i += NTHR) {
        int k4 = i >> 7, c = i & 127;
        wih4[k4][c] = make_float4(W_ih[(4*k4+0)*G4 + c], W_ih[(4*k4+1)*G4 + c],
                                  W_ih[(4*k4+2)*G4 + c], W_ih[(4*k4+3)*G4 + c]);
    }
    for (int i = tid; i < (HS/4) * G4; i += NTHR) {
        int k4 = i >> 7, c = i & 127;
        whh4[k4][c] = make_float4(W_hh[(4*k4+0)*G4 + c], W_hh[(4*k4+1)*G4 + c],
                                  W_hh[(4*k4+2)*G4 + c], W_hh[(4*k4+3)*G4 + c]);
    }
    for (int i = tid; i < (HS/4) * HS; i += NTHR) {
        int k4 = i >> 5, c = i & 31;
        wq4[k4][c] = make_float4(W_q[(4*k4+0)*HS + c], W_q[(4*k4+1)*HS + c],
                                 W_q[(4*k4+2)*HS + c], W_q[(4*k4+3)*HS + c]);
    }

    // ---- stage adj rows to LDS once ----
    {
        const int n16_per_row = KPAD / 8;           // 316 uint4 per row
        for (int i = tid; i < ROWS * n16_per_row; i += NTHR) {
            int r = i / n16_per_row, o = i - r * n16_per_row;
            ((uint4*)(adj_lds + r * ADJW))[o] =
                ((const uint4*)(adj_bf + (size_t)(base + r) * KPAD))[o];
        }
    }
    for (int i = tid; i < ROWS * HPAD; i += NTHR) {
        (&h_lds[0][0])[i] = 0.0f;
        (&c_lds[0][0])[i] = 0.0f;
    }
    __syncthreads();

    for (int t = 0; t < TT; t++) {
        const unsigned phase = (unsigned)(t + 1);
        ushort_t* qbuf = qT + (size_t)(RING ? t : (t & 1)) * QT_SLICE;

        // ---- P1b: q = tanh(h @ W_q + b_q); one q value per thread ----
        {
            float a = bqv;
#pragma unroll
            for (int k4 = 0; k4 < HS/4; k4++) {
                float4 hv = *(const float4*)&h_lds[nq][k4*4];
                float4 w = wq4[k4][hq];
                a = fmaf(hv.x, w.x, a);
                a = fmaf(hv.y, w.y, a);
                a = fmaf(hv.z, w.z, a);
                a = fmaf(hv.w, w.w, a);
            }
            q_lds[nq][hq] = tanh_fast(a);
        }
        __syncthreads();

        // ---- publish q: packed uint, agent-scope relaxed (write-through to LLC) ----
        if (tid < 256) {
            const int h0 = tid >> 3;       // 0..31
            const int pr = tid & 7;        // node pair
            unsigned val = (unsigned)f2bf(q_lds[2*pr][h0])
                         | ((unsigned)f2bf(q_lds[2*pr + 1][h0]) << 16);
            unsigned* p = (unsigned*)(qbuf + (size_t)h0 * KPAD + base) + pr;
            __hip_atomic_store(p, val, __ATOMIC_RELAXED, __HIP_MEMORY_SCOPE_AGENT);
        }

        // ==== drain shadow: local work overlaps the store->LLC round trip ====
        if (lane < 32) {
            const int node = 2*wv + (lane >> 4), k = lane & 15;
            const int gn = base + node;
            x_lds[node][k] = (gn < BSN) ? x[(size_t)gn * (TT*DIN) + (size_t)t*DIN + k] : 0.0f;
        }
#pragma unroll
        for (int j = 0; j < 2; j++) {
            const int nn = 2*wv + j;
            float a0 = bu0, a1 = bu1;
#pragma unroll
            for (int k4 = 0; k4 < DIN/4; k4++) {
                float4 xv = *(const float4*)&x_lds[nn][k4*4];
                float4 w0 = wih4[k4][u2];
                float4 w1 = wih4[k4][u2 + 64];
                a0 = fmaf(xv.x, w0.x, a0); a1 = fmaf(xv.x, w1.x, a1);
                a0 = fmaf(xv.y, w0.y, a0); a1 = fmaf(xv.y, w1.y, a1);
                a0 = fmaf(xv.z, w0.z, a0); a1 = fmaf(xv.z, w1.z, a1);
                a0 = fmaf(xv.w, w0.w, a0); a1 = fmaf(xv.w, w1.w, a1);
            }
#pragma unroll
            for (int k4 = 0; k4 < HS/4; k4++) {
                float4 hv = *(const float4*)&h_lds[nn][k4*4];
                float4 w0 = whh4[k4][u2];
                float4 w1 = whh4[k4][u2 + 64];
                a0 = fmaf(hv.x, w0.x, a0); a1 = fmaf(hv.x, w1.x, a1);
                a0 = fmaf(hv.y, w0.y, a0); a1 = fmaf(hv.y, w1.y, a1);
                a0 = fmaf(hv.z, w0.z, a0); a1 = fmaf(hv.z, w1.z, a1);
                a0 = fmaf(hv.w, w0.w, a0); a1 = fmaf(hv.w, w1.w, a1);
            }
            gates_lds[nn][u2]      = sigmoid_fast(a0);
            gates_lds[nn][u2 + 64] = (u2 < HS) ? tanh_fast(a1) : sigmoid_fast(a1);
        }

        // ---- drain q stores, then arrive ----
        asm volatile("s_waitcnt vmcnt(0)" ::: "memory");
        __syncthreads();
        if (tid == 0) {
            __hip_atomic_store(flags + blk * FLAGSTRIDE, phase,
                               __ATOMIC_RELAXED, __HIP_MEMORY_SCOPE_AGENT);
        }

        // ---- wait: thread i polls block i's flag (pure spin, spread lines) ----
        if (tid < NBLK) {
            const unsigned* f = flags + tid * FLAGSTRIDE;
            while (__hip_atomic_load(f, __ATOMIC_RELAXED, __HIP_MEMORY_SCOPE_AGENT) < phase) {}
        }
        __syncthreads();

        // ---- P2: agg = adj(LDS) @ q(LLC); wave w: contiguous chunks [10w, 10w+10) ----
        {
            floatx4 acc0 = {0.f,0.f,0.f,0.f}, acc1 = {0.f,0.f,0.f,0.f};
            const int mcol = lane & 15;
            const int kb   = lane >> 4;
            const ushort_t* arow = adj_lds + mcol * ADJW + kb*8;   // LDS

            if constexpr (RING) {
                const ushort_t* q0r = qbuf + (size_t)mcol        * KPAD + kb*8;
                const ushort_t* q1r = qbuf + (size_t)(mcol + 16) * KPAD + kb*8;
                if (wv < 7) p2_full<10>(arow, q0r, q1r, wv * 10, acc0, acc1);
                else        p2_full<9>(arow, q0r, q1r, 70,       acc0, acc1);
            } else {
                const u64_t* q0 = (const u64_t*)(qbuf + (size_t)mcol        * KPAD) + kb*2;
                const u64_t* q1 = (const u64_t*)(qbuf + (size_t)(mcol + 16) * KPAD) + kb*2;
                const int cbeg = wv * 10;
                const int cend = (cbeg + 10 < NCHUNK) ? cbeg + 10 : NCHUNK;
                for (int c = cbeg; c < cend; c++) {
                    bf16x8 av = *(const bf16x8*)(arow + c*32);
                    union { u64_t u[2]; bf16x8 v; } b0, b1;
                    b0.u[0] = QLOAD(q0 + c*8);
                    b0.u[1] = QLOAD(q0 + c*8 + 1);
                    b1.u[0] = QLOAD(q1 + c*8);
                    b1.u[1] = QLOAD(q1 + c*8 + 1);
                    acc0 = __builtin_amdgcn_mfma_f32_16x16x32_bf16(av, b0.v, acc0, 0, 0, 0);
                    acc1 = __builtin_amdgcn_mfma_f32_16x16x32_bf16(av, b1.v, acc1, 0, 0, 0);
                }
            }

            // D layout: col=lane&15, row=(lane>>4)*4+reg
#pragma unroll
            for (int r = 0; r < 4; r++) {
                part[wv][0][kb*4 + r][mcol] = acc0[r];
                part[wv][1][kb*4 + r][mcol] = acc1[r];
            }
        }
        __syncthreads();

        // ---- P3: cell/hidden update + fused output head ----
        {
            const int ntile = hq >> 4, col = hq & 15;
            float agg = 0.0f;
#pragma unroll
            for (int w = 0; w < 8; w++) agg += part[w][ntile][nq][col];
            float iv = gates_lds[nq][hq];
            float fv = gates_lds[nq][HS + hq];
            float gv = gates_lds[nq][2*HS + hq];
            float ov = gates_lds[nq][3*HS + hq];
            float cv = fv * (c_lds[nq][hq] + agg) + iv * gv;
            float hv = ov * tanh_fast(cv);
            c_lds[nq][hq] = cv;
            h_lds[nq][hq] = hv;
            float p = hv * wdv;
            p += __shfl_xor(p, 16);
            p += __shfl_xor(p, 8);
            p += __shfl_xor(p, 4);
            p += __shfl_xor(p, 2);
            p += __shfl_xor(p, 1);
            if (hq == 0) {
                int gn = base + nq;
                if (gn < BSN) out[(size_t)gn * TT + t] = p + bdv;
            }
        }
        __syncthreads();
    }
}

extern "C" void kernel_launch(void* const* d_in, const int* in_sizes, int n_in,
                              void* d_out, int out_size, void* d_ws, size_t ws_size,
                              hipStream_t stream) {
    const float* x    = (const float*)d_in[0];
    const float* adj  = (const float*)d_in[1];
    const float* W_ih = (const float*)d_in[2];
    const float* W_hh = (const float*)d_in[3];
    const float* bias = (const float*)d_in[4];
    const float* W_q  = (const float*)d_in[5];
    const float* b_q  = (const float*)d_in[6];
    const float* W_d  = (const float*)d_in[7];
    const float* b_d  = (const float*)d_in[8];
    float* out = (float*)d_out;

    unsigned* flags = (unsigned*)((char*)d_ws + WS_FLAGS_OFF);
    ushort_t* adj_bf = (ushort_t*)((char*)d_ws + WS_ADJ_OFF);
    ushort_t* qT = (ushort_t*)((char*)d_ws + WS_QT_OFF);

    const bool ring = (ws_size >= WS_NEED_RING);   // constant across calls -> graph-safe

    // sentinel first: if the cooperative launch below is rejected, out keeps 12345.0
    hipLaunchKernelGGL(sentinel, dim3((out_size + 255) / 256), dim3(256), 0, stream,
                       out, out_size);
    hipLaunchKernelGGL(prep, dim3(2048), dim3(256), 0, stream, adj, adj_bf, qT, flags);

    const ushort_t* adj_bf_c = adj_bf;
    void* args[] = {
        (void*)&x, (void*)&W_ih, (void*)&W_hh, (void*)&bias, (void*)&W_q,
        (void*)&b_q, (void*)&W_d, (void*)&b_d, (void*)&adj_bf_c, (void*)&qT,
        (void*)&flags, (void*)&out
    };
    if (ring) {
        hipLaunchCooperativeKernel((void*)&rgcn_main<true>, dim3(NBLK), dim3(NTHR),
                                   args, 0, stream);
    } else {
        hipLaunchCooperativeKernel((void*)&rgcn_main<false>, dim3(NBLK), dim3(NTHR),
                                   args, 0, stream);
    }
}